// Round 4
// baseline (697.261 us; speedup 1.0000x reference)
//
#include <hip/hip_runtime.h>

// 2-layer tanh RNN, B=2048, S=512, I=1, H=64, O=1.
// TWO waves per batch element (block=128) so per-lane weight state fits the
// 128-VGPR budget the allocator actually grants (rounds 2-3 proved it spills
// rather than allocate >128):
//   wave0, lane i: W_hh0[i][0:64] + W_ih1[i][0:32]   (96 floats, registers)
//   wave1, lane i: W_hh1[i][0:64] + W_ih1[i][32:64]  (96 floats, registers)
// Software-pipelined: iteration k computes h1[k] (wave0) and h2[k-1] (wave1).
// The W_ih1 partial sum a2p crosses from wave0 to wave1 through LDS.
// h1 and a2p are ping-pong buffered by k&1; h2 is wave1-private (in-wave DS
// ordering). Exactly ONE __syncthreads per step.

#define HID 64
#define SEQ 512

__device__ __forceinline__ float tanh_fast(float x) {
    // tanh(x) = 1 - 2/(exp(2x)+1);  exp(2x) = exp2(x * 2*log2(e))
    float e = __builtin_amdgcn_exp2f(x * 2.8853900817779268f);  // v_exp_f32
    return 1.0f - 2.0f * __builtin_amdgcn_rcpf(e + 1.0f);       // v_rcp_f32
}

#define FMA4(acc, warr, base, vec)            \
    acc = fmaf(warr[(base)+0], (vec).x, acc); \
    acc = fmaf(warr[(base)+1], (vec).y, acc); \
    acc = fmaf(warr[(base)+2], (vec).z, acc); \
    acc = fmaf(warr[(base)+3], (vec).w, acc);

__global__ void __launch_bounds__(128)
rnn2_kernel(const float* __restrict__ x,      // [B][SEQ] (I=1)
            const float* __restrict__ W_ih0,  // [HID][1]
            const float* __restrict__ W_hh0,  // [HID][HID]
            const float* __restrict__ b_ih0,  // [HID]
            const float* __restrict__ b_hh0,  // [HID]
            const float* __restrict__ W_ih1,  // [HID][HID]
            const float* __restrict__ W_hh1,  // [HID][HID]
            const float* __restrict__ b_ih1,  // [HID]
            const float* __restrict__ b_hh1,  // [HID]
            const float* __restrict__ fc_W,   // [1][HID]
            const float* __restrict__ fc_b,   // [1]
            float* __restrict__ out)          // [B]
{
    __shared__ __align__(16) float x_lds[SEQ];
    __shared__ __align__(16) float h1buf[2][HID];
    __shared__ __align__(16) float a2p_buf[2][HID];
    __shared__ __align__(16) float h2_lds[HID];

    const int tid  = threadIdx.x;
    const int lane = tid & 63;
    const int wid  = tid >> 6;        // 0 = layer-1 wave, 1 = layer-2 wave
    const int b    = blockIdx.x;

    // --- Per-wave weight rows into registers (96 floats/lane) ---
    float wa[HID], wb[HID / 2];
    const float* wa_src = wid ? &W_hh1[lane * HID] : &W_hh0[lane * HID];
    const float* wb_src = wid ? &W_ih1[lane * HID + 32] : &W_ih1[lane * HID];
#pragma unroll
    for (int j = 0; j < HID; j += 4) {
        const float4 v = *reinterpret_cast<const float4*>(&wa_src[j]);
        wa[j] = v.x; wa[j+1] = v.y; wa[j+2] = v.z; wa[j+3] = v.w;
    }
#pragma unroll
    for (int j = 0; j < HID / 2; j += 4) {
        const float4 v = *reinterpret_cast<const float4*>(&wb_src[j]);
        wb[j] = v.x; wb[j+1] = v.y; wb[j+2] = v.z; wb[j+3] = v.w;
    }
    const float win0  = W_ih0[lane];
    const float bias0 = b_ih0[lane] + b_hh0[lane];
    const float bias1 = b_ih1[lane] + b_hh1[lane];

    // --- Stage x sequence into LDS (coalesced, both waves) ---
#pragma unroll
    for (int t = 0; t < SEQ / 128; ++t)
        x_lds[t * 128 + tid] = x[(size_t)b * SEQ + t * 128 + tid];

    // --- Prologue ---
    if (wid == 0) {
        // x_lds[0] was written by lane 0 of THIS wave -> in-wave DS ordering.
        const float h1n = tanh_fast(fmaf(x_lds[0], win0, bias0));
        h1buf[0][lane] = h1n;                 // h1[0]
    } else {
        h2_lds[lane] = 0.0f;                  // h2[-1] = 0
    }
    __syncthreads();

    // --- Main loop: iter k computes h1[k] (wave0) and h2[k-1] (wave1) ---
#pragma unroll 2
    for (int k = 1; k < SEQ; ++k) {
        const float* h1rd = h1buf[(k - 1) & 1];   // h1[k-1]
        float a2q = 0.f, a3a = 0.f, a3b = 0.f;    // wave1 partials (live across barrier)

        if (wid == 0) {
            float a1a = 0.f, a1b = 0.f, a2p = 0.f;
#pragma unroll
            for (int j = 0; j < HID; j += 8) {
                const float4 p = *reinterpret_cast<const float4*>(&h1rd[j]);
                const float4 q = *reinterpret_cast<const float4*>(&h1rd[j + 4]);
                FMA4(a1a, wa, j,     p);
                FMA4(a1b, wa, j + 4, q);
                if (j < HID / 2) {               // a2p = W_ih1[:,0:32] . h1[k-1][0:32]
                    FMA4(a2p, wb, j,     p);
                    FMA4(a2p, wb, j + 4, q);
                }
            }
            const float h1n = tanh_fast(a1a + a1b + fmaf(x_lds[k], win0, bias0));
            a2p_buf[k & 1][lane] = a2p;
            h1buf[k & 1][lane]   = h1n;          // h1[k]
        } else {
#pragma unroll
            for (int j = 0; j < HID; j += 8) {   // a3 = W_hh1 . h2[k-2]
                const float4 r = *reinterpret_cast<const float4*>(&h2_lds[j]);
                const float4 t = *reinterpret_cast<const float4*>(&h2_lds[j + 4]);
                FMA4(a3a, wa, j,     r);
                FMA4(a3b, wa, j + 4, t);
            }
#pragma unroll
            for (int j = 0; j < HID / 2; j += 8) {  // a2q = W_ih1[:,32:64] . h1[k-1][32:64]
                const float4 p = *reinterpret_cast<const float4*>(&h1rd[32 + j]);
                const float4 q = *reinterpret_cast<const float4*>(&h1rd[32 + j + 4]);
                FMA4(a2q, wb, j,     p);
                FMA4(a2q, wb, j + 4, q);
            }
        }

        __syncthreads();   // a2p/h1[k] published; wave1 done reading old buffers

        if (wid == 1) {
            const float a2p = a2p_buf[k & 1][lane];
            const float h2n = tanh_fast(a2p + a2q + a3a + a3b + bias1);
            h2_lds[lane] = h2n;                  // h2[k-1] (wave1-private)
        }
    }

    // --- Epilogue: h2[SEQ-1] from h1[SEQ-1] (in h1buf[1]) and h2[SEQ-2] ---
    {
        const float* h1rd = h1buf[(SEQ - 1) & 1];
        float a2q = 0.f, a3a = 0.f, a3b = 0.f;
        if (wid == 0) {
            float a2p = 0.f;
#pragma unroll
            for (int j = 0; j < HID / 2; j += 8) {
                const float4 p = *reinterpret_cast<const float4*>(&h1rd[j]);
                const float4 q = *reinterpret_cast<const float4*>(&h1rd[j + 4]);
                FMA4(a2p, wb, j,     p);
                FMA4(a2p, wb, j + 4, q);
            }
            a2p_buf[0][lane] = a2p;
        } else {
#pragma unroll
            for (int j = 0; j < HID; j += 8) {
                const float4 r = *reinterpret_cast<const float4*>(&h2_lds[j]);
                const float4 t = *reinterpret_cast<const float4*>(&h2_lds[j + 4]);
                FMA4(a3a, wa, j,     r);
                FMA4(a3b, wa, j + 4, t);
            }
#pragma unroll
            for (int j = 0; j < HID / 2; j += 8) {
                const float4 p = *reinterpret_cast<const float4*>(&h1rd[32 + j]);
                const float4 q = *reinterpret_cast<const float4*>(&h1rd[32 + j + 4]);
                FMA4(a2q, wb, j,     p);
                FMA4(a2q, wb, j + 4, q);
            }
        }
        __syncthreads();

        if (wid == 1) {
            const float h2last = tanh_fast(a2p_buf[0][lane] + a2q + a3a + a3b + bias1);
            // Final FC: out[b] = sum_i h2last[i] * fc_W[i] + fc_b
            float v = h2last * fc_W[lane];
#pragma unroll
            for (int off = 32; off > 0; off >>= 1)
                v += __shfl_xor(v, off, 64);
            if (lane == 0)
                out[b] = v + fc_b[0];
        }
    }
}

extern "C" void kernel_launch(void* const* d_in, const int* in_sizes, int n_in,
                              void* d_out, int out_size, void* d_ws, size_t ws_size,
                              hipStream_t stream) {
    const float* x     = (const float*)d_in[0];
    const float* W_ih0 = (const float*)d_in[1];
    const float* W_hh0 = (const float*)d_in[2];
    const float* b_ih0 = (const float*)d_in[3];
    const float* b_hh0 = (const float*)d_in[4];
    const float* W_ih1 = (const float*)d_in[5];
    const float* W_hh1 = (const float*)d_in[6];
    const float* b_ih1 = (const float*)d_in[7];
    const float* b_hh1 = (const float*)d_in[8];
    const float* fc_W  = (const float*)d_in[9];
    const float* fc_b  = (const float*)d_in[10];

    rnn2_kernel<<<dim3(2048), dim3(128), 0, stream>>>(
        x, W_ih0, W_hh0, b_ih0, b_hh0, W_ih1, W_hh1, b_ih1, b_hh1,
        fc_W, fc_b, (float*)d_out);
}

// Round 5
// 282.268 us; speedup vs baseline: 2.4702x; 2.4702x over previous
//
#include <hip/hip_runtime.h>

// 2-layer tanh RNN, B=2048, S=512, I=1, H=64, O=1.
// One wave per batch element. Lane i owns hidden unit i. All three weight
// rows live in VGPRs as PACKED F16 PAIRS (192 f16 = 96 VGPRs), consumed by
// v_dot2_f32_f16 (__builtin_amdgcn_fdot2: 2 MACs/instr, f32 accumulate).
// This fits the 128-VGPR bracket the allocator actually grants (rounds 2-4
// showed it will not allocate >128 and demotes/spills anything bigger).
// Software-pipelined: iteration k computes h1[k] and h2[k-1]; h passes
// between steps through wave-private LDS as f16 (uniform-address 16B reads =
// broadcast). Single-wave block -> in-order DS, no __syncthreads.
// asm "memory" barriers stop TBAA/LICM from hoisting the (loop-invariant-
// address) h reloads across the h stores.

#define HID 64
#define SEQ 512

typedef _Float16 half2_t __attribute__((ext_vector_type(2)));
typedef _Float16 half8_t __attribute__((ext_vector_type(8)));

__device__ __forceinline__ float tanh_fast(float x) {
    // tanh(x) = 1 - 2/(exp(2x)+1);  exp(2x) = exp2(x * 2*log2(e))
    float e = __builtin_amdgcn_exp2f(x * 2.8853900817779268f);  // v_exp_f32
    return 1.0f - 2.0f * __builtin_amdgcn_rcpf(e + 1.0f);       // v_rcp_f32
}

__device__ __forceinline__ float dot2(half2_t a, half2_t b, float c) {
#if defined(__has_builtin) && __has_builtin(__builtin_amdgcn_fdot2)
    return __builtin_amdgcn_fdot2(a, b, c, false);   // v_dot2_f32_f16
#else
    return fmaf((float)a.x, (float)b.x, fmaf((float)a.y, (float)b.y, c));
#endif
}

__device__ __forceinline__ half2_t pr(half8_t v, int t) {  // t compile-time
    half2_t r; r.x = v[2 * t]; r.y = v[2 * t + 1]; return r;
}

__global__ void __launch_bounds__(64, 4)
rnn2_kernel(const float* __restrict__ x,      // [B][SEQ] (I=1)
            const float* __restrict__ W_ih0,  // [HID][1]
            const float* __restrict__ W_hh0,  // [HID][HID]
            const float* __restrict__ b_ih0,  // [HID]
            const float* __restrict__ b_hh0,  // [HID]
            const float* __restrict__ W_ih1,  // [HID][HID]
            const float* __restrict__ W_hh1,  // [HID][HID]
            const float* __restrict__ b_ih1,  // [HID]
            const float* __restrict__ b_hh1,  // [HID]
            const float* __restrict__ fc_W,   // [1][HID]
            const float* __restrict__ fc_b,   // [1]
            float* __restrict__ out)          // [B]
{
    __shared__ __align__(16) float    x_lds[SEQ];
    __shared__ __align__(16) _Float16 h1_lds[HID];
    __shared__ __align__(16) _Float16 h2_lds[HID];

    const int lane = threadIdx.x;   // 0..63 = hidden unit
    const int b    = blockIdx.x;    // batch element

    // --- Weight rows -> packed f16 pairs in registers (96 VGPRs) ---
    half2_t w0h[HID / 2], wi1h[HID / 2], w1h[HID / 2];
#pragma unroll
    for (int j = 0; j < HID; j += 4) {
        const float4 a = *reinterpret_cast<const float4*>(&W_hh0[lane * HID + j]);
        const float4 c = *reinterpret_cast<const float4*>(&W_ih1[lane * HID + j]);
        const float4 d = *reinterpret_cast<const float4*>(&W_hh1[lane * HID + j]);
        w0h [j/2]   = half2_t{(_Float16)a.x, (_Float16)a.y};
        w0h [j/2+1] = half2_t{(_Float16)a.z, (_Float16)a.w};
        wi1h[j/2]   = half2_t{(_Float16)c.x, (_Float16)c.y};
        wi1h[j/2+1] = half2_t{(_Float16)c.z, (_Float16)c.w};
        w1h [j/2]   = half2_t{(_Float16)d.x, (_Float16)d.y};
        w1h [j/2+1] = half2_t{(_Float16)d.z, (_Float16)d.w};
    }
    const float win0  = W_ih0[lane];
    const float bias0 = b_ih0[lane] + b_hh0[lane];
    const float bias1 = b_ih1[lane] + b_hh1[lane];

    // --- Stage x sequence into LDS (coalesced, f32) ---
#pragma unroll
    for (int t = 0; t < SEQ / HID; ++t)
        x_lds[t * HID + lane] = x[(size_t)b * SEQ + t * HID + lane];

    // --- Prologue: h2[-1] = 0; h1[0] = tanh(x0*win0 + bias0) ---
    h2_lds[lane] = (_Float16)0.0f;
    h1_lds[lane] = (_Float16)tanh_fast(fmaf(x_lds[0], win0, bias0));
    asm volatile("" ::: "memory");

    // --- Main loop: iter k computes h1[k] and h2[k-1] ---
    // Entering iter k: h1_lds = h1[k-1], h2_lds = h2[k-2].
#pragma unroll 1
    for (int k = 1; k < SEQ; ++k) {
        float a1a = 0.f, a1b = 0.f;   // W_hh0 . h1[k-1]          -> h1[k]
        float a2a = 0.f, a2b = 0.f;   // W_ih1.h1[k-1] + W_hh1.h2[k-2] -> h2[k-1]
#pragma unroll
        for (int j = 0; j < 8; ++j) {  // 16B chunk = 8 units = 4 pairs
            const half8_t c1 = *reinterpret_cast<const half8_t*>(&h1_lds[8 * j]);
            const half8_t c2 = *reinterpret_cast<const half8_t*>(&h2_lds[8 * j]);
            a1a = dot2(w0h [4*j+0], pr(c1,0), a1a);
            a1b = dot2(w0h [4*j+1], pr(c1,1), a1b);
            a1a = dot2(w0h [4*j+2], pr(c1,2), a1a);
            a1b = dot2(w0h [4*j+3], pr(c1,3), a1b);
            a2a = dot2(wi1h[4*j+0], pr(c1,0), a2a);
            a2b = dot2(wi1h[4*j+1], pr(c1,1), a2b);
            a2a = dot2(wi1h[4*j+2], pr(c1,2), a2a);
            a2b = dot2(wi1h[4*j+3], pr(c1,3), a2b);
            a2a = dot2(w1h [4*j+0], pr(c2,0), a2a);
            a2b = dot2(w1h [4*j+1], pr(c2,1), a2b);
            a2a = dot2(w1h [4*j+2], pr(c2,2), a2a);
            a2b = dot2(w1h [4*j+3], pr(c2,3), a2b);
        }
        const float h1n = tanh_fast(a1a + a1b + fmaf(x_lds[k], win0, bias0));
        const float h2n = tanh_fast(a2a + a2b + bias1);
        asm volatile("" ::: "memory");   // reads above stay above the stores
        h1_lds[lane] = (_Float16)h1n;    // h1[k]
        h2_lds[lane] = (_Float16)h2n;    // h2[k-1]
        asm volatile("" ::: "memory");   // next-iter reads stay below stores
    }

    // --- Epilogue: h2[SEQ-1] from h1[SEQ-1] and h2[SEQ-2] ---
    float a2a = 0.f, a2b = 0.f;
#pragma unroll
    for (int j = 0; j < 8; ++j) {
        const half8_t c1 = *reinterpret_cast<const half8_t*>(&h1_lds[8 * j]);
        const half8_t c2 = *reinterpret_cast<const half8_t*>(&h2_lds[8 * j]);
        a2a = dot2(wi1h[4*j+0], pr(c1,0), a2a);
        a2b = dot2(wi1h[4*j+1], pr(c1,1), a2b);
        a2a = dot2(wi1h[4*j+2], pr(c1,2), a2a);
        a2b = dot2(wi1h[4*j+3], pr(c1,3), a2b);
        a2a = dot2(w1h [4*j+0], pr(c2,0), a2a);
        a2b = dot2(w1h [4*j+1], pr(c2,1), a2b);
        a2a = dot2(w1h [4*j+2], pr(c2,2), a2a);
        a2b = dot2(w1h [4*j+3], pr(c2,3), a2b);
    }
    const float h2last = tanh_fast(a2a + a2b + bias1);

    // --- Final FC: out[b] = sum_i h2last[i] * fc_W[i] + fc_b ---
    float v = h2last * fc_W[lane];
#pragma unroll
    for (int off = 32; off > 0; off >>= 1)
        v += __shfl_xor(v, off, 64);
    if (lane == 0)
        out[b] = v + fc_b[0];
}

extern "C" void kernel_launch(void* const* d_in, const int* in_sizes, int n_in,
                              void* d_out, int out_size, void* d_ws, size_t ws_size,
                              hipStream_t stream) {
    const float* x     = (const float*)d_in[0];
    const float* W_ih0 = (const float*)d_in[1];
    const float* W_hh0 = (const float*)d_in[2];
    const float* b_ih0 = (const float*)d_in[3];
    const float* b_hh0 = (const float*)d_in[4];
    const float* W_ih1 = (const float*)d_in[5];
    const float* W_hh1 = (const float*)d_in[6];
    const float* b_ih1 = (const float*)d_in[7];
    const float* b_hh1 = (const float*)d_in[8];
    const float* fc_W  = (const float*)d_in[9];
    const float* fc_b  = (const float*)d_in[10];

    rnn2_kernel<<<dim3(2048), dim3(64), 0, stream>>>(
        x, W_ih0, W_hh0, b_ih0, b_hh0, W_ih1, W_hh1, b_ih1, b_hh1,
        fc_W, fc_b, (float*)d_out);
}